// Round 6
// baseline (206.362 us; speedup 1.0000x reference)
//
#include <hip/hip_runtime.h>
#include <math.h>

// Problem constants (B=64, J=17, H=W=128)
#define BJ    1088               // B*J maps per tensor
#define NMAP  (2 * BJ)           // 2176 maps (pred then gt)
#define HW    16384              // 128*128
#define NTH   256                // 4 waves per block
#define WPB   4
#define NBLK  (NMAP / WPB)       // 544 blocks

// Monotonic unsigned key for float bits: orders like float compare.
__device__ __forceinline__ unsigned int ford(unsigned int u) {
    return (u & 0x80000000u) ? ~u : (u | 0x80000000u);
}
__device__ __forceinline__ unsigned int ford_inv(unsigned int o) {
    return (o & 0x80000000u) ? (o & 0x7fffffffu) : ~o;
}

// ONE WAVE PER MAP — zero block-level serialization (no LDS, no barrier, no
// atomics; R5 showed the per-block reduce+atomic tail halves streaming duty
// cycle). Sweep 1: 64 float4/lane, 4 independent per-component max chains
// (deep MLP). One butterfly u64 reduce. Sweep 2: re-read (L2/L3-warm) for
// the masked distance sum. Lane 0 stores d[map].
__global__ __launch_bounds__(NTH, 2) void hm_stats(const float* __restrict__ outp,
                                                   const float* __restrict__ tgtp,
                                                   float* __restrict__ d)
{
    const int t    = threadIdx.x;
    const int lane = t & 63;
    const int wave = t >> 6;
    const int m    = blockIdx.x * WPB + wave;      // [0, NMAP)
    const float* __restrict__ src = (m < BJ)
        ? (outp + (size_t)m * HW)
        : (tgtp + (size_t)(m - BJ) * HW);
    const float4* __restrict__ s4 = (const float4*)src;

    // ---- sweep 1: max + first-argmax, 4 independent component chains
    float mx0 = -INFINITY, mx1 = -INFINITY, mx2 = -INFINITY, mx3 = -INFINITY;
    int   ix0 = 0, ix1 = 1, ix2 = 2, ix3 = 3;
#pragma unroll
    for (int k = 0; k < 64; ++k) {                 // lane-local idx grows with k
        const float4 v = s4[lane + (k << 6)];
        const int base = (lane + (k << 6)) << 2;
        if (v.x > mx0) { mx0 = v.x; ix0 = base;     }
        if (v.y > mx1) { mx1 = v.y; ix1 = base + 1; }
        if (v.z > mx2) { mx2 = v.z; ix2 = base + 2; }
        if (v.w > mx3) { mx3 = v.w; ix3 = base + 3; }
    }
    // merge 4 chains + cross-lane via u64 key: (ord(val)<<32)|~idx — max = (max val, min idx)
    unsigned long long k0 = ((unsigned long long)ford(__float_as_uint(mx0)) << 32) | (unsigned int)~ix0;
    unsigned long long k1 = ((unsigned long long)ford(__float_as_uint(mx1)) << 32) | (unsigned int)~ix1;
    unsigned long long k2 = ((unsigned long long)ford(__float_as_uint(mx2)) << 32) | (unsigned int)~ix2;
    unsigned long long k3 = ((unsigned long long)ford(__float_as_uint(mx3)) << 32) | (unsigned int)~ix3;
    unsigned long long key = k0 > k1 ? k0 : k1;
    key = k2 > key ? k2 : key;
    key = k3 > key ? k3 : key;
#pragma unroll
    for (int off = 32; off >= 1; off >>= 1) {      // butterfly: every lane gets result
        const unsigned long long ok = __shfl_xor(key, off, 64);
        key = (ok > key) ? ok : key;
    }

    const float maxv = __uint_as_float(ford_inv((unsigned int)(key >> 32)));
    const int   midx = (int)~(unsigned int)(key & 0xffffffffu);
    const float ym  = (float)(midx >> 7);          // reference: idx // H (H=128 stride)
    const float xm  = (float)(midx & 127);
    const float thv = maxv * 0.5f;

    // ---- sweep 2: masked distance sum, re-read (just-streamed, cache-warm)
    float s0 = 0.f, s1 = 0.f, s2 = 0.f, s3 = 0.f;
    float c0 = 0.f, c1 = 0.f, c2 = 0.f, c3 = 0.f;
#pragma unroll
    for (int k = 0; k < 64; ++k) {
        const float4 v = s4[lane + (k << 6)];
        const int g4 = lane + (k << 6);
        const float dy  = (float)(g4 >> 5) - ym;   // all 4 elems share a row
        const float dy2 = dy * dy;
        const float cb  = (float)((g4 << 2) & 127) - xm;
        {
            const float dx = cb;        const float ds = __builtin_amdgcn_sqrtf(fmaf(dx, dx, dy2));
            const float mk = (v.x > thv) ? 1.0f : 0.0f;  s0 = fmaf(mk, ds, s0);  c0 += mk;
        }
        {
            const float dx = cb + 1.0f; const float ds = __builtin_amdgcn_sqrtf(fmaf(dx, dx, dy2));
            const float mk = (v.y > thv) ? 1.0f : 0.0f;  s1 = fmaf(mk, ds, s1);  c1 += mk;
        }
        {
            const float dx = cb + 2.0f; const float ds = __builtin_amdgcn_sqrtf(fmaf(dx, dx, dy2));
            const float mk = (v.z > thv) ? 1.0f : 0.0f;  s2 = fmaf(mk, ds, s2);  c2 += mk;
        }
        {
            const float dx = cb + 3.0f; const float ds = __builtin_amdgcn_sqrtf(fmaf(dx, dx, dy2));
            const float mk = (v.w > thv) ? 1.0f : 0.0f;  s3 = fmaf(mk, ds, s3);  c3 += mk;
        }
    }
    float s = (s0 + s1) + (s2 + s3);
    float c = (c0 + c1) + (c2 + c3);
#pragma unroll
    for (int off = 32; off >= 1; off >>= 1) {
        s += __shfl_xor(s, off, 64);
        c += __shfl_xor(c, off, 64);
    }
    if (lane == 0) {
        const float mean = s / fmaxf(c, 1.0f);
        const float dd   = (c > 0.0f) ? (mean / 181.02f) : 1.0f;   // MAX_DIST
        d[m] = (maxv > 0.0f) ? dd : 0.0f;
    }
}

// Single-block final reduction: sum |gt - pred| / J / B
__global__ __launch_bounds__(256) void finalize(const float* __restrict__ d,
                                                float* __restrict__ out)
{
    __shared__ float rs[4];
    const int t = threadIdx.x;
    float acc = 0.0f;
    for (int i = t; i < BJ; i += 256)
        acc += fabsf(d[BJ + i] - d[i]);
#pragma unroll
    for (int off = 32; off >= 1; off >>= 1)
        acc += __shfl_down(acc, off, 64);
    const int wave = t >> 6, lane = t & 63;
    if (lane == 0) rs[wave] = acc;
    __syncthreads();
    if (t == 0) {
        acc = rs[0] + rs[1] + rs[2] + rs[3];
        out[0] = acc / 17.0f / 64.0f;              // / J / B, reference order
    }
}

extern "C" void kernel_launch(void* const* d_in, const int* in_sizes, int n_in,
                              void* d_out, int out_size, void* d_ws, size_t ws_size,
                              hipStream_t stream) {
    const float* outp = (const float*)d_in[0];     // [64,17,128,128] f32
    const float* tgtp = (const float*)d_in[1];
    float* d = (float*)d_ws;                       // NMAP floats

    hm_stats<<<dim3(NBLK), dim3(NTH), 0, stream>>>(outp, tgtp, d);
    finalize<<<dim3(1),    dim3(256), 0, stream>>>(d, (float*)d_out);
}

// Round 7
// 155.792 us; speedup vs baseline: 1.3246x; 1.3246x over previous
//
#include <hip/hip_runtime.h>
#include <math.h>

// Problem constants (B=64, J=17, H=W=128)
#define BJ    1088               // B*J maps per tensor
#define NMAP  (2 * BJ)           // 2176 maps (pred then gt)
#define HW    16384              // 128*128
#define NTH   512                // 8 waves per block
#define NWAVE (NTH / 64)
#define F4PT  (HW / 4 / NTH)     // 8 float4 per thread

// Monotonic unsigned key for float bits: orders like float compare.
__device__ __forceinline__ unsigned int ford(unsigned int u) {
    return (u & 0x80000000u) ? ~u : (u | 0x80000000u);
}
__device__ __forceinline__ unsigned int ford_inv(unsigned int o) {
    return (o & 0x80000000u) ? (o & 0x7fffffffu) : ~o;
}

// One 512-thread block per map. ONE HBM sweep (guaranteed by explicit LDS
// staging — R4 proved the compiler reloads "register-kept" data): burst all
// 8 float4/thread, stage to LDS + max-scan in the same pass. One barrier
// (key exchange only). Masked sum re-reads each thread's OWN staged LDS
// values (no 2nd barrier; ds_read_b128 2-way conflict = free), v_sqrt +
// predicated fmaf. 66 KB LDS -> 2 blocks/CU; co-resident block's load
// burst hides this block's reduce/sum tail.
__global__ __launch_bounds__(NTH, 4) void hm_stats(const float* __restrict__ outp,
                                                   const float* __restrict__ tgtp,
                                                   float* __restrict__ d)
{
    __shared__ float hm[HW];                       // 64 KB
    __shared__ unsigned long long rk[NWAVE];
    __shared__ float rs[NWAVE], rc[NWAVE];

    const int m = blockIdx.x;                      // [0, NMAP)
    const int t = threadIdx.x;
    const float* __restrict__ src = (m < BJ)
        ? (outp + (size_t)m * HW)
        : (tgtp + (size_t)(m - BJ) * HW);
    const float4* __restrict__ s4 = (const float4*)src;
    float4* hm4 = (float4*)hm;

    // ---- single load burst (8 float4 outstanding), then stage + 4-chain scan
    float4 v[F4PT];
#pragma unroll
    for (int k = 0; k < F4PT; ++k) v[k] = s4[t + k * NTH];

    float mx0 = -INFINITY, mx1 = -INFINITY, mx2 = -INFINITY, mx3 = -INFINITY;
    int   ix0 = 0, ix1 = 1, ix2 = 2, ix3 = 3;
#pragma unroll
    for (int k = 0; k < F4PT; ++k) {               // per-thread idx grows with k -> '>' keeps first
        hm4[t + k * NTH] = v[k];
        const int base = (t + k * NTH) << 2;
        if (v[k].x > mx0) { mx0 = v[k].x; ix0 = base;     }
        if (v[k].y > mx1) { mx1 = v[k].y; ix1 = base + 1; }
        if (v[k].z > mx2) { mx2 = v[k].z; ix2 = base + 2; }
        if (v[k].w > mx3) { mx3 = v[k].w; ix3 = base + 3; }
    }

    // merge 4 chains via u64 keys: (ord(val)<<32)|~idx — max = (max val, min idx)
    unsigned long long k0 = ((unsigned long long)ford(__float_as_uint(mx0)) << 32) | (unsigned int)~ix0;
    unsigned long long k1 = ((unsigned long long)ford(__float_as_uint(mx1)) << 32) | (unsigned int)~ix1;
    unsigned long long k2 = ((unsigned long long)ford(__float_as_uint(mx2)) << 32) | (unsigned int)~ix2;
    unsigned long long k3 = ((unsigned long long)ford(__float_as_uint(mx3)) << 32) | (unsigned int)~ix3;
    unsigned long long key = k0 > k1 ? k0 : k1;
    key = k2 > key ? k2 : key;
    key = k3 > key ? k3 : key;
#pragma unroll
    for (int off = 32; off >= 1; off >>= 1) {
        const unsigned long long ok = __shfl_xor(key, off, 64);
        key = (ok > key) ? ok : key;
    }
    const int wave = t >> 6, lane = t & 63;
    if (lane == 0) rk[wave] = key;
    __syncthreads();                               // the ONLY data barrier
    unsigned long long bkey = rk[0];
#pragma unroll
    for (int w = 1; w < NWAVE; ++w) bkey = (rk[w] > bkey) ? rk[w] : bkey;

    const float maxv = __uint_as_float(ford_inv((unsigned int)(bkey >> 32)));
    const int   midx = (int)~(unsigned int)(bkey & 0xffffffffu);
    const float ym  = (float)(midx >> 7);          // reference: idx // H (H=128 stride)
    const float xm  = (float)(midx & 127);
    const float thv = maxv * 0.5f;

    // ---- masked distance sum from own staged LDS values (no barrier needed)
    float s = 0.0f, c = 0.0f;
#pragma unroll
    for (int k = 0; k < F4PT; ++k) {
        const float4 w = hm4[t + k * NTH];
        const int g4 = t + k * NTH;
        const float dy  = (float)(g4 >> 5) - ym;   // all 4 elems share a row
        const float dy2 = dy * dy;
        const float cb  = (float)((g4 << 2) & 127) - xm;
        {
            const float dx = cb;        const float ds = __builtin_amdgcn_sqrtf(fmaf(dx, dx, dy2));
            const float mk = (w.x > thv) ? 1.0f : 0.0f;  s = fmaf(mk, ds, s);  c += mk;
        }
        {
            const float dx = cb + 1.0f; const float ds = __builtin_amdgcn_sqrtf(fmaf(dx, dx, dy2));
            const float mk = (w.y > thv) ? 1.0f : 0.0f;  s = fmaf(mk, ds, s);  c += mk;
        }
        {
            const float dx = cb + 2.0f; const float ds = __builtin_amdgcn_sqrtf(fmaf(dx, dx, dy2));
            const float mk = (w.z > thv) ? 1.0f : 0.0f;  s = fmaf(mk, ds, s);  c += mk;
        }
        {
            const float dx = cb + 3.0f; const float ds = __builtin_amdgcn_sqrtf(fmaf(dx, dx, dy2));
            const float mk = (w.w > thv) ? 1.0f : 0.0f;  s = fmaf(mk, ds, s);  c += mk;
        }
    }

#pragma unroll
    for (int off = 32; off >= 1; off >>= 1) {
        s += __shfl_xor(s, off, 64);
        c += __shfl_xor(c, off, 64);
    }
    if (lane == 0) { rs[wave] = s; rc[wave] = c; }
    __syncthreads();
    if (t == 0) {
#pragma unroll
        for (int w = 1; w < NWAVE; ++w) { s += rs[w]; c += rc[w]; }
        const float mean = s / fmaxf(c, 1.0f);
        const float dd   = (c > 0.0f) ? (mean / 181.02f) : 1.0f;   // MAX_DIST
        d[m] = (maxv > 0.0f) ? dd : 0.0f;
    }
}

// Single-block final reduction: sum |gt - pred| / J / B
__global__ __launch_bounds__(256) void finalize(const float* __restrict__ d,
                                                float* __restrict__ out)
{
    __shared__ float rs[4];
    const int t = threadIdx.x;
    float acc = 0.0f;
    for (int i = t; i < BJ; i += 256)
        acc += fabsf(d[BJ + i] - d[i]);
#pragma unroll
    for (int off = 32; off >= 1; off >>= 1)
        acc += __shfl_down(acc, off, 64);
    const int wave = t >> 6, lane = t & 63;
    if (lane == 0) rs[wave] = acc;
    __syncthreads();
    if (t == 0) {
        acc = rs[0] + rs[1] + rs[2] + rs[3];
        out[0] = acc / 17.0f / 64.0f;              // / J / B, reference order
    }
}

extern "C" void kernel_launch(void* const* d_in, const int* in_sizes, int n_in,
                              void* d_out, int out_size, void* d_ws, size_t ws_size,
                              hipStream_t stream) {
    const float* outp = (const float*)d_in[0];     // [64,17,128,128] f32
    const float* tgtp = (const float*)d_in[1];
    float* d = (float*)d_ws;                       // NMAP floats

    hm_stats<<<dim3(NMAP), dim3(NTH), 0, stream>>>(outp, tgtp, d);
    finalize<<<dim3(1),    dim3(256), 0, stream>>>(d, (float*)d_out);
}